// Round 12
// baseline (529.391 us; speedup 1.0000x reference)
//
#include <hip/hip_runtime.h>

typedef unsigned int u32;
typedef unsigned short u16;
typedef short bf16x8 __attribute__((ext_vector_type(8)));   // 8 bf16 (4 VGPRs)
typedef float f32x4 __attribute__((ext_vector_type(4)));    // MFMA accumulator

#define NCB 256   // blocks for count/place passes (fixed)
#define GEMM_BLOCKS 512

__device__ __forceinline__ float bf2f(u16 h) { return __uint_as_float(((u32)h) << 16); }
__device__ __forceinline__ u16 f2bf(float f) {
    u32 u = __float_as_uint(f);
    return (u16)((u + 0x7fffu + ((u >> 16) & 1u)) >> 16);   // RNE
}

// ---------------- diagnostic fallback: ws too small ----------------
__global__ __launch_bounds__(256) void k_sentinel(u16* out, int n) {
    int i = blockIdx.x * 256 + threadIdx.x;
    if (i < n) out[i] = f2bf(-7.0f);
}

// ---------------- dtype detection: flag=0 bf16-packed, flag=1 f32 ----------------
__global__ void k_detect(const u32* x, int* flag) {
    int lane = threadIdx.x;  // 64 threads
    int c = 0;
    for (int j = 0; j < 4; ++j) {
        u32 u = x[lane * 4 + j];
        u32 e = (u >> 7) & 0xffu;
        if ((e >= 0x30u && e <= 0x47u) || ((u & 0x7fffu) == 0u)) ++c;
    }
    for (int d = 32; d; d >>= 1) c += __shfl_down(c, d, 64);
    if (lane == 0) *flag = (c < 128) ? 1 : 0;
}

// ---------------- front: x-convert + param-convert + bucket count (NO deg atomics)
__global__ __launch_bounds__(256) void k_front(
    const void* x, const int* dstv, const int* flag, int bucketed,
    uint4* X, int* C, int E, int N, int chunk, int cvtB,
    const void* s1l, const void* s1r, const void* shl, const void* shr,
    const void* s2l, const void* s2r, const void* sb1, const void* sbh,
    const void* sb2,
    u32* w1l, u32* w1r, u32* whl, u32* whr, u32* w2l, u32* w2r,
    float* bf1, float* bfh, float* bf2) {
    __shared__ int hist[256];
    int b = blockIdx.x, t = threadIdx.x;
    if (b < cvtB) {
        int i = b * 256 + t;
        if (i >= N * 16) return;
        if (*flag) {
            const float4* s = (const float4*)x;
            float4 a = s[2 * i], c4 = s[2 * i + 1];
            uint4 o;
            o.x = (u32)f2bf(a.x) | ((u32)f2bf(a.y) << 16);
            o.y = (u32)f2bf(a.z) | ((u32)f2bf(a.w) << 16);
            o.z = (u32)f2bf(c4.x) | ((u32)f2bf(c4.y) << 16);
            o.w = (u32)f2bf(c4.z) | ((u32)f2bf(c4.w) << 16);
            X[i] = o;
        } else {
            X[i] = ((const uint4*)x)[i];
        }
    } else if (b < cvtB + 134) {
        int bb = b - cvtB;
        int fl = *flag;
        auto cv = [&](const void* src, u32* dst, int base) {
            int i = base + t;
            if (fl) {
                const float* s = (const float*)src;
                dst[i] = (u32)f2bf(s[2 * i]) | ((u32)f2bf(s[2 * i + 1]) << 16);
            } else {
                dst[i] = ((const u32*)src)[i];
            }
        };
        auto cb = [&](const void* src, float* dst, int i) {
            dst[i] = fl ? ((const float*)src)[i] : bf2f(((const u16*)src)[i]);
        };
        if      (bb <  32) cv(s1l, w1l, bb * 256);
        else if (bb <  64) cv(s1r, w1r, (bb - 32) * 256);
        else if (bb <  96) cv(shl, whl, (bb - 64) * 256);
        else if (bb < 128) cv(shr, whr, (bb - 96) * 256);
        else if (bb < 130) cv(s2l, w2l, (bb - 128) * 256);
        else if (bb < 132) cv(s2r, w2r, (bb - 130) * 256);
        else if (bb == 132) {
            if (t < 128) cb(sb1, bf1, t);
            else         cb(sbh, bfh, t - 128);
        } else {
            if (t < 8) cb(sb2, bf2, t);
        }
    } else if (bucketed) {
        int cb2 = b - cvtB - 134;    // count block 0..255
        hist[t] = 0;
        __syncthreads();
        int e0 = cb2 * chunk;
        int e1 = min(e0 + chunk, E);
        for (int e = e0 + t; e < e1; e += 256) {
            int d = min(max(dstv[e], 0), N - 1);
            atomicAdd(&hist[d >> 8], 1);   // LDS only
        }
        __syncthreads();
        C[cb2 * 256 + t] = hist[t];        // transposed: coalesced write
    }
}

// ---------------- per-bucket: exclusive scan of C over blocks + total -------------
__global__ __launch_bounds__(256) void k_scanT(int* C, int* T) {
    __shared__ int sm[256];
    int bu = blockIdx.x, t = threadIdx.x;
    int v = C[t * 256 + bu];
    sm[t] = v;
    __syncthreads();
    for (int off = 1; off < 256; off <<= 1) {
        int u = (t >= off) ? sm[t - off] : 0;
        __syncthreads();
        sm[t] += u;
        __syncthreads();
    }
    C[t * 256 + bu] = sm[t] - v;       // block-prefix within bucket
    if (t == 255) T[bu] = sm[255];     // bucket total
}

// ---------------- exclusive scan of bucket totals -> bucket bases -----------------
__global__ __launch_bounds__(256) void k_scanB(const int* T, int* B, int nbuk) {
    __shared__ int sm[256];
    int t = threadIdx.x;
    int v = (t < nbuk) ? T[t] : 0;
    sm[t] = v;
    __syncthreads();
    for (int off = 1; off < 256; off <<= 1) {
        int u = (t >= off) ? sm[t - off] : 0;
        __syncthreads();
        sm[t] += u;
        __syncthreads();
    }
    B[t] = sm[t] - v;
}

// ---------------- place edges into bucket-segmented pairs ----------------
__global__ __launch_bounds__(256) void k_place(const int* srcv, const int* dstv,
                                               const int* C, const int* Bb,
                                               u32* pairs, int E, int N, int chunk) {
    __shared__ int base[256], cnt[256];
    int t = threadIdx.x;
    base[t] = Bb[t] + C[blockIdx.x * 256 + t];
    cnt[t] = 0;
    __syncthreads();
    int e0 = blockIdx.x * chunk;
    int e1 = min(e0 + chunk, E);
    for (int e = e0 + t; e < e1; e += 256) {
        int d = min(max(dstv[e], 0), N - 1);
        int s = min(max(srcv[e], 0), N - 1);
        int b = d >> 8;
        int pos = base[b] + atomicAdd(&cnt[b], 1);
        pos = min(max(pos, 0), E - 1);
        pairs[pos] = ((u32)s << 8) | (u32)(d & 255);
    }
}

// ---------------- per-bucket: local degree count + scan -> rowptr; scatter adj ----
__global__ __launch_bounds__(256) void k_fillb2(const u32* pairs, const int* Bb,
                                                const int* T, int* rowptr,
                                                int* adj, int E, int N, int nbuk) {
    int bu = blockIdx.x;
    int n0 = bu << 8;
    int nn = min(N - n0, 256);
    __shared__ int dcnt[256], sm[256], cur[256];
    int t = threadIdx.x;
    dcnt[t] = 0;
    __syncthreads();
    int s0 = min(max(Bb[bu], 0), E);
    int s1 = min(s0 + max(T[bu], 0), E);
    for (int e = s0 + t; e < s1; e += 256) {
        int ld = (int)(pairs[e] & 255u);
        atomicAdd(&dcnt[min(ld, nn - 1)], 1);
    }
    __syncthreads();
    int v = dcnt[t];
    sm[t] = v;
    __syncthreads();
    for (int off = 1; off < 256; off <<= 1) {
        int u = (t >= off) ? sm[t - off] : 0;
        __syncthreads();
        sm[t] += u;
        __syncthreads();
    }
    int excl = sm[t] - v;
    cur[t] = excl;
    if (t < nn) rowptr[n0 + t] = s0 + excl;
    if (bu == nbuk - 1 && t == 0) rowptr[N] = E;
    __syncthreads();
    for (int e = s0 + t; e < s1; e += 256) {
        u32 pc = pairs[e];
        int ld = min((int)(pc & 255u), nn - 1);
        int src = (int)(pc >> 8);
        int slot = atomicAdd(&cur[ld], 1);
        int idx = min(max(s0 + slot, 0), E - 1);
        adj[idx] = src;
    }
}

// ---------------- fallback CSR for N > 65536 (global atomics path) ----------------
__global__ __launch_bounds__(256) void k_zero(int* deg, int N) {
    int i = blockIdx.x * 256 + threadIdx.x;
    if (i < N) deg[i] = 0;
}
__global__ __launch_bounds__(256) void k_deg(const int* dstv, int* deg, int E, int N) {
    int e = blockIdx.x * 256 + threadIdx.x;
    if (e >= E) return;
    int d = dstv[e]; d = min(max(d, 0), N - 1);
    atomicAdd(&deg[d], 1);
}
__global__ __launch_bounds__(512) void k_scan1(const int* deg, int* r0,
                                               int* bsums, int N) {
    __shared__ int sm[512];
    int i = blockIdx.x * 512 + threadIdx.x;
    int v = (i < N) ? deg[i] : 0;
    sm[threadIdx.x] = v;
    __syncthreads();
    for (int off = 1; off < 512; off <<= 1) {
        int t = (threadIdx.x >= off) ? sm[threadIdx.x - off] : 0;
        __syncthreads();
        sm[threadIdx.x] += t;
        __syncthreads();
    }
    if (i < N) r0[i] = sm[threadIdx.x] - v;
    if (threadIdx.x == 511) bsums[blockIdx.x] = sm[511];
}
__global__ __launch_bounds__(128) void k_scan2f(int* bsums, int nb) {
    __shared__ int sm[128];
    int v = (threadIdx.x < nb) ? bsums[threadIdx.x] : 0;
    sm[threadIdx.x] = v;
    __syncthreads();
    for (int off = 1; off < 128; off <<= 1) {
        int t = (threadIdx.x >= off) ? sm[threadIdx.x - off] : 0;
        __syncthreads();
        sm[threadIdx.x] += t;
        __syncthreads();
    }
    if (threadIdx.x < nb) bsums[threadIdx.x] = sm[threadIdx.x] - v;
}
__global__ __launch_bounds__(512) void k_scan3f(const int* r0, const int* bsums,
                                                int* rowptr, int N, int E) {
    int i = blockIdx.x * 512 + threadIdx.x;
    if (i < N) rowptr[i] = r0[i] + bsums[blockIdx.x];
    if (i == 0) rowptr[N] = E;
}
__global__ __launch_bounds__(256) void k_fill(const int* srcv, const int* dstv,
                                              const int* rowptr, int* deg,
                                              int* adj, int E, int N) {
    int e = blockIdx.x * 256 + threadIdx.x;
    if (e >= E) return;
    int d = dstv[e]; d = min(max(d, 0), N - 1);
    int slot = atomicSub(&deg[d], 1) - 1;
    int idx = rowptr[d] + slot;
    idx = min(max(idx, 0), E - 1);
    adj[idx] = srcv[e];
}

// ---------------- mean aggregation: one wave per node, masked full-ILP -----------
__device__ __forceinline__ void acc8m(uint4 u, float m, float* s) {
    const u32* pu = (const u32*)&u;
#pragma unroll
    for (int t = 0; t < 4; ++t) {
        s[2 * t]     = fmaf(__uint_as_float(pu[t] << 16), m, s[2 * t]);
        s[2 * t + 1] = fmaf(__uint_as_float(pu[t] & 0xffff0000u), m, s[2 * t + 1]);
    }
}

__global__ __launch_bounds__(256) void k_aggregate(const uint4* F, const int* rowptr,
                                                   const int* adj, uint4* A,
                                                   int N, int E) {
    int wid = (int)((blockIdx.x * 256u + threadIdx.x) >> 6);
    int lane = threadIdx.x & 63;
    if (wid >= N) return;
    int beg = rowptr[wid], end = rowptr[wid + 1];
    beg = min(max(beg, 0), E);
    end = min(max(end, beg), E);
    int g = lane >> 4, l = lane & 15;
    float s[8] = {0.f, 0.f, 0.f, 0.f, 0.f, 0.f, 0.f, 0.f};
    for (int j = beg + g; j < end; j += 16) {
        int i1 = j + 4, i2 = j + 8, i3 = j + 12;
        float m1 = (i1 < end) ? 1.f : 0.f;
        float m2 = (i2 < end) ? 1.f : 0.f;
        float m3 = (i3 < end) ? 1.f : 0.f;
        int a0 = min(max(adj[j], 0), N - 1);
        int a1 = min(max(adj[min(i1, end - 1)], 0), N - 1);
        int a2 = min(max(adj[min(i2, end - 1)], 0), N - 1);
        int a3 = min(max(adj[min(i3, end - 1)], 0), N - 1);
        uint4 u0 = F[(size_t)a0 * 16 + l];
        uint4 u1 = F[(size_t)a1 * 16 + l];
        uint4 u2 = F[(size_t)a2 * 16 + l];
        uint4 u3 = F[(size_t)a3 * 16 + l];
        acc8m(u0, 1.f, s);
        acc8m(u1, m1, s);
        acc8m(u2, m2, s);
        acc8m(u3, m3, s);
    }
#pragma unroll
    for (int k = 0; k < 8; ++k) {
        s[k] += __shfl_xor(s[k], 16, 64);
        s[k] += __shfl_xor(s[k], 32, 64);
    }
    if (g == 0) {
        float inv = 1.f / fmaxf((float)(end - beg), 1.f);
        uint4 r; u32* pr = (u32*)&r;
#pragma unroll
        for (int t = 0; t < 4; ++t)
            pr[t] = (u32)f2bf(s[2 * t] * inv) | ((u32)f2bf(s[2 * t + 1] * inv) << 16);
        A[(size_t)wid * 16 + l] = r;
    }
}

// ---------------- butterfly segmented reduction: sum v[j][r] over 16 lanes --------
// v laid out [j*4+r]; returns the j = 4*b0+2*b1+b2 sum (all 16 lanes get a j).
__device__ __forceinline__ float bfly8(const float* v, int r, bool b0, bool b1, bool b2) {
    float w0[4];
#pragma unroll
    for (int jj = 0; jj < 4; ++jj) {
        float snd = b0 ? v[jj * 4 + r] : v[(jj + 4) * 4 + r];
        float rec = __shfl_xor(snd, 1, 64);
        w0[jj] = (b0 ? v[(jj + 4) * 4 + r] : v[jj * 4 + r]) + rec;
    }
    float w1v[2];
#pragma unroll
    for (int kk = 0; kk < 2; ++kk) {
        float snd = b1 ? w1v[0] * 0.f + w0[kk] : w0[kk + 2];
        snd = b1 ? w0[kk] : w0[kk + 2];
        float rec = __shfl_xor(snd, 2, 64);
        w1v[kk] = (b1 ? w0[kk + 2] : w0[kk]) + rec;
    }
    float snd = b2 ? w1v[0] : w1v[1];
    float rec = __shfl_xor(snd, 4, 64);
    float w2v = (b2 ? w1v[1] : w1v[0]) + rec;
    w2v += __shfl_xor(w2v, 8, 64);
    return w2v;
}

// ---------------- persistent grid-stride GEMM -------------------------------------
// LAYER 0: h1 = relu(Agg@Wl^T + b + Xin@Wr^T) -> OutX (bf16, own-rows aliasing ok)
// LAYER 1: h2 = elu(...); fused head Y = h2@W2l^T, R = h2@W2r^T + b2 (f32)
// Wsh staged ONCE per block (512 blocks, 2/CU); waves grid-stride over 16-row
// tiles with A-fragment prefetch (8 independent 16B loads hidden under K-loop).
template <int LAYER>
__global__ __launch_bounds__(256, 2) void k_gemmP(
    const u16* Agg, const u16* Xin, const u32* Wl, const u32* Wr,
    const float* bias, u16* OutX,
    const u32* W2l, const u32* W2r, const float* b2p,
    float* Y, float* R, int N) {
    __shared__ __align__(16) u16 Wsh[32768];                 // 64 KB
    __shared__ float W2sh[(LAYER == 1) ? 2048 : 4];          // +8 KB (layer 2)
    int t = threadIdx.x;
#pragma unroll
    for (int i = 0; i < 16; ++i) {
        int f = i * 256 + t;
        int c = f >> 9, s = (f >> 6) & 7, q = (f >> 4) & 3, n = f & 15;
        int o = c * 16 + n;
        int k = s * 32 + q * 8;
        uint4 v;
        if (k < 128) v = *(const uint4*)(Wl + (size_t)o * 64 + (k >> 1));
        else         v = *(const uint4*)(Wr + (size_t)o * 64 + ((k - 128) >> 1));
        *(uint4*)(Wsh + f * 8) = v;
    }
    if (LAYER == 1) {
#pragma unroll
        for (int i = t; i < 512; i += 256) {
            u32 wa = W2l[i], wb = W2r[i];
            W2sh[2 * i]            = bf2f((u16)(wa & 0xffffu));
            W2sh[2 * i + 1]        = bf2f((u16)(wa >> 16));
            W2sh[1024 + 2 * i]     = bf2f((u16)(wb & 0xffffu));
            W2sh[1024 + 2 * i + 1] = bf2f((u16)(wb >> 16));
        }
    }
    __syncthreads();

    int lane = t & 63;
    int wid = t >> 6;
    int quad = lane >> 4, k15 = lane & 15;
    int kq = quad * 8;
    int ntiles = (N + 15) >> 4;
    int tstride = gridDim.x * 4;
    int tile = blockIdx.x * 4 + wid;
    const u16* lbase = Wsh + quad * 128 + k15 * 8;

    auto loadA = [&](bf16x8* fr, int tl) {
        int mrow = min(tl * 16 + k15, N - 1);
#pragma unroll
        for (int s = 0; s < 8; ++s) {
            int k = s * 32 + kq;
            const u16* p = (k < 128) ? (Agg + (size_t)mrow * 128 + k)
                                     : (Xin + (size_t)mrow * 128 + (k - 128));
            fr[s] = *(const bf16x8*)p;
        }
    };

    bf16x8 curA[8];
    if (tile < ntiles) loadA(curA, tile);

    for (; tile < ntiles; tile += tstride) {
        int nt = tile + tstride;
        bf16x8 nxtA[8];
        loadA(nxtA, (nt < ntiles) ? nt : tile);   // prefetch (discarded if invalid)

        f32x4 acc[8];
#pragma unroll
        for (int c = 0; c < 8; ++c) acc[c] = (f32x4){0.f, 0.f, 0.f, 0.f};
#pragma unroll
        for (int c = 0; c < 8; ++c) {
#pragma unroll
            for (int s = 0; s < 8; ++s) {
                bf16x8 b = *(const bf16x8*)(lbase + (c * 8 + s) * 512);
                acc[c] = __builtin_amdgcn_mfma_f32_16x16x32_bf16(curA[s], b, acc[c], 0, 0, 0);
            }
        }

        int m0 = tile * 16;
        if (LAYER == 0) {
#pragma unroll
            for (int c = 0; c < 8; ++c) {
                int o = c * 16 + k15;
                float bv = bias[o];
#pragma unroll
                for (int r = 0; r < 4; ++r) {
                    int m = m0 + quad * 4 + r;
                    float v = acc[c][r] + bv;
                    v = fmaxf(v, 0.f);
                    if (m < N) OutX[(size_t)m * 128 + o] = f2bf(v);
                }
            }
        } else {
            // elu
#pragma unroll
            for (int c = 0; c < 8; ++c) {
                float bv = bias[c * 16 + k15];
#pragma unroll
                for (int r = 0; r < 4; ++r) {
                    float v = acc[c][r] + bv;
                    acc[c][r] = (v > 0.f) ? v : expm1f(v);
                }
            }
            // partials py/pr[j][r]
            float py[32], pr[32];
#pragma unroll
            for (int i = 0; i < 32; ++i) { py[i] = 0.f; pr[i] = 0.f; }
#pragma unroll
            for (int j = 0; j < 8; ++j) {
#pragma unroll
                for (int c = 0; c < 8; ++c) {
                    float w1 = W2sh[j * 128 + c * 16 + k15];
                    float w2 = W2sh[1024 + j * 128 + c * 16 + k15];
#pragma unroll
                    for (int r = 0; r < 4; ++r) {
                        py[j * 4 + r] = fmaf(acc[c][r], w1, py[j * 4 + r]);
                        pr[j * 4 + r] = fmaf(acc[c][r], w2, pr[j * 4 + r]);
                    }
                }
            }
            bool bb0 = (k15 & 1) != 0, bb1 = (k15 & 2) != 0, bb2 = (k15 & 4) != 0;
            int jmine = 4 * (k15 & 1) + (k15 & 2) + ((k15 >> 2) & 1);
#pragma unroll
            for (int r = 0; r < 4; ++r) {
                float yv = bfly8(py, r, bb0, bb1, bb2);
                float rv = bfly8(pr, r, bb0, bb1, bb2);
                int m = m0 + quad * 4 + r;
                if (m < N) {
                    if (k15 < 8) Y[(size_t)m * 8 + jmine] = yv;
                    else         R[(size_t)m * 8 + jmine] = rv + b2p[jmine];
                }
            }
        }
#pragma unroll
        for (int s = 0; s < 8; ++s) curA[s] = nxtA[s];
    }
}

// ---------------- final: mean-aggregate Y + R + log_softmax ----------------------
__global__ __launch_bounds__(256) void k_agg8sm(const float* Y, const float* R,
                                                const int* rowptr, const int* adj,
                                                const int* flag, void* Out,
                                                int N, int E) {
    int t = blockIdx.x * 256 + threadIdx.x;
    int n = t >> 3;
    int o = t & 7;
    if (n >= N) return;
    int beg = rowptr[n], end = rowptr[n + 1];
    beg = min(max(beg, 0), E);
    end = min(max(end, beg), E);
    float s = 0.f;
    int j = beg;
    for (; j + 1 < end; j += 2) {
        int a0 = min(max(adj[j], 0), N - 1);
        int a1 = min(max(adj[j + 1], 0), N - 1);
        s += Y[(size_t)a0 * 8 + o];
        s += Y[(size_t)a1 * 8 + o];
    }
    if (j < end) {
        int a0 = min(max(adj[j], 0), N - 1);
        s += Y[(size_t)a0 * 8 + o];
    }
    float acc = s / fmaxf((float)(end - beg), 1.f) + R[(size_t)n * 8 + o];
    float mx = acc;
#pragma unroll
    for (int d = 1; d < 8; d <<= 1) mx = fmaxf(mx, __shfl_xor(mx, d, 64));
    float ex = expf(acc - mx), se = ex;
#pragma unroll
    for (int d = 1; d < 8; d <<= 1) se += __shfl_xor(se, d, 64);
    float v = acc - mx - logf(se);
    if (*flag) ((float*)Out)[(size_t)n * 8 + o] = v;
    else       ((u16*)Out)[(size_t)n * 8 + o] = f2bf(v);
}

// ---------------- launch ----------------
extern "C" void kernel_launch(void* const* d_in, const int* in_sizes, int n_in,
                              void* d_out, int out_size, void* d_ws, size_t ws_size,
                              hipStream_t stream) {
    const void* x   = d_in[0];
    const int* ei   = (const int*)d_in[1];
    const int N = in_sizes[0] / 128;
    const int E = in_sizes[1] / 2;
    const int* srcv = ei;
    const int* dstv = ei + E;
    const int NBUK = (N + 255) >> 8;         // buckets of 256 nodes
    const int bucketed = (NBUK <= 256) ? 1 : 0;
    const int chunk = (E + NCB - 1) / NCB;
    const int cvtB = (N * 16 + 255) / 256;
    const int nbA = (N + 511) / 512;

    auto rnd = [](size_t b) { return (b + 255) & ~(size_t)255; };
    size_t need = rnd(256)                    // flag
                + rnd((size_t)N * 4)          // deg (fallback)
                + rnd((size_t)N * 4)          // r0 (fallback)
                + rnd((size_t)(N + 1) * 4)    // rowptr
                + rnd(4096)                   // bsums (fallback)
                + rnd(256 * NCB * 4)          // C matrix
                + rnd(1024) + rnd(1024)       // T, B
                + rnd((size_t)E * 4)          // adj
                + 2 * rnd((size_t)N * 256)    // X, A
                + 2 * rnd((size_t)N * 32)     // Y, R
                + 4 * rnd(32768) + 2 * rnd(2048) + 2 * rnd(512) + rnd(64);
    if (ws_size < need) {
        k_sentinel<<<(out_size + 255) / 256, 256, 0, stream>>>((u16*)d_out, out_size);
        return;
    }

    char* p = (char*)d_ws;
    auto carve = [&](size_t bytes) { char* r = p; p += (bytes + 255) & ~(size_t)255; return r; };
    int* flag   = (int*)carve(256);
    int* deg    = (int*)carve((size_t)N * 4);
    int* r0     = (int*)carve((size_t)N * 4);
    int* rowptr = (int*)carve((size_t)(N + 1) * 4);
    int* bsums  = (int*)carve(4096);
    int* C      = (int*)carve(256 * NCB * 4);
    int* T      = (int*)carve(1024);
    int* B      = (int*)carve(1024);
    int* adj    = (int*)carve((size_t)E * 4);
    u32* X      = (u32*)carve((size_t)N * 256);   // [N,128] packed bf16
    u32* A      = (u32*)carve((size_t)N * 256);   // agg buffer
    float* Y    = (float*)carve((size_t)N * 32);  // [N,8] f32
    float* R    = (float*)carve((size_t)N * 32);
    u32* w1l = (u32*)carve(32768); u32* w1r = (u32*)carve(32768);
    u32* whl = (u32*)carve(32768); u32* whr = (u32*)carve(32768);
    u32* w2l = (u32*)carve(2048);  u32* w2r = (u32*)carve(2048);
    float* bf1 = (float*)carve(512); float* bfh = (float*)carve(512);
    float* bf2 = (float*)carve(64);
    u32* pairs = A;                  // consumed by k_fillb2 before first aggregate
    (void)n_in;

    // 1: dtype detect
    k_detect<<<1, 64, 0, stream>>>((const u32*)x, flag);
    // 2: convert x + params + bucket count (LDS-only atomics)
    k_front<<<cvtB + 134 + (bucketed ? 256 : 0), 256, 0, stream>>>(
        x, dstv, flag, bucketed, (uint4*)X, C, E, N, chunk, cvtB,
        d_in[3], d_in[5], d_in[6], d_in[8], d_in[9], d_in[11],
        d_in[4], d_in[7], d_in[10],
        w1l, w1r, whl, whr, w2l, w2r, bf1, bfh, bf2);
    if (bucketed) {
        k_scanT<<<NBUK, 256, 0, stream>>>(C, T);
        k_scanB<<<1, 256, 0, stream>>>(T, B, NBUK);
        k_place<<<NCB, 256, 0, stream>>>(srcv, dstv, C, B, pairs, E, N, chunk);
        k_fillb2<<<NBUK, 256, 0, stream>>>(pairs, B, T, rowptr, adj, E, N, NBUK);
    } else {
        k_zero<<<(N + 255) / 256, 256, 0, stream>>>(deg, N);
        k_deg<<<(E + 255) / 256, 256, 0, stream>>>(dstv, deg, E, N);
        k_scan1<<<nbA, 512, 0, stream>>>(deg, r0, bsums, N);
        k_scan2f<<<1, 128, 0, stream>>>(bsums, nbA);
        k_scan3f<<<nbA, 512, 0, stream>>>(r0, bsums, rowptr, N, E);
        k_fill<<<(E + 255) / 256, 256, 0, stream>>>(srcv, dstv, rowptr, deg, adj, E, N);
    }

    int aggBlocks = (int)(((size_t)N * 64 + 255) / 256);
    int perNode8 = (int)(((size_t)N * 8 + 255) / 256);

    // L1: A=mean(X); h1=relu(A@W1l^T+b1+X@W1r^T) -> X (own-rows aliasing, safe)
    k_aggregate<<<aggBlocks, 256, 0, stream>>>((const uint4*)X, rowptr, adj, (uint4*)A, N, E);
    k_gemmP<0><<<GEMM_BLOCKS, 256, 0, stream>>>((const u16*)A, (const u16*)X, w1l, w1r,
                                                bf1, (u16*)X, nullptr, nullptr, nullptr,
                                                nullptr, nullptr, N);
    // L2: A=mean(h1); fused gemm+elu+head -> Y,R (h2 never materialized)
    k_aggregate<<<aggBlocks, 256, 0, stream>>>((const uint4*)X, rowptr, adj, (uint4*)A, N, E);
    k_gemmP<1><<<GEMM_BLOCKS, 256, 0, stream>>>((const u16*)A, (const u16*)X, whl, whr,
                                                bfh, nullptr, w2l, w2r, bf2, Y, R, N);
    // out = log_softmax(mean_agg(Y) + R)
    k_agg8sm<<<perNode8, 256, 0, stream>>>(Y, R, rowptr, adj, flag, d_out, N, E);
}

// Round 13
// 244.510 us; speedup vs baseline: 2.1651x; 2.1651x over previous
//
#include <hip/hip_runtime.h>

typedef unsigned int u32;
typedef unsigned short u16;
typedef short bf16x8 __attribute__((ext_vector_type(8)));   // 8 bf16 (4 VGPRs)
typedef float f32x4 __attribute__((ext_vector_type(4)));    // MFMA accumulator

#define NCB 256   // blocks for count/place passes (fixed)

__device__ __forceinline__ float bf2f(u16 h) { return __uint_as_float(((u32)h) << 16); }
__device__ __forceinline__ u16 f2bf(float f) {
    u32 u = __float_as_uint(f);
    return (u16)((u + 0x7fffu + ((u >> 16) & 1u)) >> 16);   // RNE
}

// ---------------- diagnostic fallback: ws too small ----------------
__global__ __launch_bounds__(256) void k_sentinel(u16* out, int n) {
    int i = blockIdx.x * 256 + threadIdx.x;
    if (i < n) out[i] = f2bf(-7.0f);
}

// ---------------- dtype detection: flag=0 bf16-packed, flag=1 f32 ----------------
__global__ void k_detect(const u32* x, int* flag) {
    int lane = threadIdx.x;  // 64 threads
    int c = 0;
    for (int j = 0; j < 4; ++j) {
        u32 u = x[lane * 4 + j];
        u32 e = (u >> 7) & 0xffu;
        if ((e >= 0x30u && e <= 0x47u) || ((u & 0x7fffu) == 0u)) ++c;
    }
    for (int d = 32; d; d >>= 1) c += __shfl_down(c, d, 64);
    if (lane == 0) *flag = (c < 128) ? 1 : 0;
}

// ---------------- front: x-convert + param-convert + bucket count (NO deg atomics)
__global__ __launch_bounds__(256) void k_front(
    const void* x, const int* dstv, const int* flag, int bucketed,
    uint4* X, int* C, int E, int N, int chunk, int cvtB,
    const void* s1l, const void* s1r, const void* shl, const void* shr,
    const void* s2l, const void* s2r, const void* sb1, const void* sbh,
    const void* sb2,
    u32* w1l, u32* w1r, u32* whl, u32* whr, u32* w2l, u32* w2r,
    float* bf1, float* bfh, float* bf2) {
    __shared__ int hist[256];
    int b = blockIdx.x, t = threadIdx.x;
    if (b < cvtB) {
        int i = b * 256 + t;
        if (i >= N * 16) return;
        if (*flag) {
            const float4* s = (const float4*)x;
            float4 a = s[2 * i], c4 = s[2 * i + 1];
            uint4 o;
            o.x = (u32)f2bf(a.x) | ((u32)f2bf(a.y) << 16);
            o.y = (u32)f2bf(a.z) | ((u32)f2bf(a.w) << 16);
            o.z = (u32)f2bf(c4.x) | ((u32)f2bf(c4.y) << 16);
            o.w = (u32)f2bf(c4.z) | ((u32)f2bf(c4.w) << 16);
            X[i] = o;
        } else {
            X[i] = ((const uint4*)x)[i];
        }
    } else if (b < cvtB + 134) {
        int bb = b - cvtB;
        int fl = *flag;
        auto cv = [&](const void* src, u32* dst, int base) {
            int i = base + t;
            if (fl) {
                const float* s = (const float*)src;
                dst[i] = (u32)f2bf(s[2 * i]) | ((u32)f2bf(s[2 * i + 1]) << 16);
            } else {
                dst[i] = ((const u32*)src)[i];
            }
        };
        auto cb = [&](const void* src, float* dst, int i) {
            dst[i] = fl ? ((const float*)src)[i] : bf2f(((const u16*)src)[i]);
        };
        if      (bb <  32) cv(s1l, w1l, bb * 256);
        else if (bb <  64) cv(s1r, w1r, (bb - 32) * 256);
        else if (bb <  96) cv(shl, whl, (bb - 64) * 256);
        else if (bb < 128) cv(shr, whr, (bb - 96) * 256);
        else if (bb < 130) cv(s2l, w2l, (bb - 128) * 256);
        else if (bb < 132) cv(s2r, w2r, (bb - 130) * 256);
        else if (bb == 132) {
            if (t < 128) cb(sb1, bf1, t);
            else         cb(sbh, bfh, t - 128);
        } else {
            if (t < 8) cb(sb2, bf2, t);
        }
    } else if (bucketed) {
        int cb2 = b - cvtB - 134;    // count block 0..255
        hist[t] = 0;
        __syncthreads();
        int e0 = cb2 * chunk;
        int e1 = min(e0 + chunk, E);
        for (int e = e0 + t; e < e1; e += 256) {
            int d = min(max(dstv[e], 0), N - 1);
            atomicAdd(&hist[d >> 8], 1);   // LDS only
        }
        __syncthreads();
        C[cb2 * 256 + t] = hist[t];        // transposed: coalesced write
    }
}

// ---------------- per-bucket: exclusive scan of C over blocks + total -------------
__global__ __launch_bounds__(256) void k_scanT(int* C, int* T) {
    __shared__ int sm[256];
    int bu = blockIdx.x, t = threadIdx.x;
    int v = C[t * 256 + bu];
    sm[t] = v;
    __syncthreads();
    for (int off = 1; off < 256; off <<= 1) {
        int u = (t >= off) ? sm[t - off] : 0;
        __syncthreads();
        sm[t] += u;
        __syncthreads();
    }
    C[t * 256 + bu] = sm[t] - v;       // block-prefix within bucket
    if (t == 255) T[bu] = sm[255];     // bucket total
}

// ---------------- exclusive scan of bucket totals -> bucket bases -----------------
__global__ __launch_bounds__(256) void k_scanB(const int* T, int* B, int nbuk) {
    __shared__ int sm[256];
    int t = threadIdx.x;
    int v = (t < nbuk) ? T[t] : 0;
    sm[t] = v;
    __syncthreads();
    for (int off = 1; off < 256; off <<= 1) {
        int u = (t >= off) ? sm[t - off] : 0;
        __syncthreads();
        sm[t] += u;
        __syncthreads();
    }
    B[t] = sm[t] - v;
}

// ---------------- place edges into bucket-segmented pairs ----------------
__global__ __launch_bounds__(256) void k_place(const int* srcv, const int* dstv,
                                               const int* C, const int* Bb,
                                               u32* pairs, int E, int N, int chunk) {
    __shared__ int base[256], cnt[256];
    int t = threadIdx.x;
    base[t] = Bb[t] + C[blockIdx.x * 256 + t];
    cnt[t] = 0;
    __syncthreads();
    int e0 = blockIdx.x * chunk;
    int e1 = min(e0 + chunk, E);
    for (int e = e0 + t; e < e1; e += 256) {
        int d = min(max(dstv[e], 0), N - 1);
        int s = min(max(srcv[e], 0), N - 1);
        int b = d >> 8;
        int pos = base[b] + atomicAdd(&cnt[b], 1);
        pos = min(max(pos, 0), E - 1);
        pairs[pos] = ((u32)s << 8) | (u32)(d & 255);
    }
}

// ---------------- per-bucket: local degree count + scan -> rowptr; scatter adj ----
__global__ __launch_bounds__(256) void k_fillb2(const u32* pairs, const int* Bb,
                                                const int* T, int* rowptr,
                                                int* adj, int E, int N, int nbuk) {
    int bu = blockIdx.x;
    int n0 = bu << 8;
    int nn = min(N - n0, 256);
    __shared__ int dcnt[256], sm[256], cur[256];
    int t = threadIdx.x;
    dcnt[t] = 0;
    __syncthreads();
    int s0 = min(max(Bb[bu], 0), E);
    int s1 = min(s0 + max(T[bu], 0), E);
    for (int e = s0 + t; e < s1; e += 256) {
        int ld = (int)(pairs[e] & 255u);
        atomicAdd(&dcnt[min(ld, nn - 1)], 1);
    }
    __syncthreads();
    int v = dcnt[t];
    sm[t] = v;
    __syncthreads();
    for (int off = 1; off < 256; off <<= 1) {
        int u = (t >= off) ? sm[t - off] : 0;
        __syncthreads();
        sm[t] += u;
        __syncthreads();
    }
    int excl = sm[t] - v;
    cur[t] = excl;
    if (t < nn) rowptr[n0 + t] = s0 + excl;
    if (bu == nbuk - 1 && t == 0) rowptr[N] = E;
    __syncthreads();
    for (int e = s0 + t; e < s1; e += 256) {
        u32 pc = pairs[e];
        int ld = min((int)(pc & 255u), nn - 1);
        int src = (int)(pc >> 8);
        int slot = atomicAdd(&cur[ld], 1);
        int idx = min(max(s0 + slot, 0), E - 1);
        adj[idx] = src;
    }
}

// ---------------- fallback CSR for N > 65536 (global atomics path) ----------------
__global__ __launch_bounds__(256) void k_zero(int* deg, int N) {
    int i = blockIdx.x * 256 + threadIdx.x;
    if (i < N) deg[i] = 0;
}
__global__ __launch_bounds__(256) void k_deg(const int* dstv, int* deg, int E, int N) {
    int e = blockIdx.x * 256 + threadIdx.x;
    if (e >= E) return;
    int d = dstv[e]; d = min(max(d, 0), N - 1);
    atomicAdd(&deg[d], 1);
}
__global__ __launch_bounds__(512) void k_scan1(const int* deg, int* r0,
                                               int* bsums, int N) {
    __shared__ int sm[512];
    int i = blockIdx.x * 512 + threadIdx.x;
    int v = (i < N) ? deg[i] : 0;
    sm[threadIdx.x] = v;
    __syncthreads();
    for (int off = 1; off < 512; off <<= 1) {
        int t = (threadIdx.x >= off) ? sm[threadIdx.x - off] : 0;
        __syncthreads();
        sm[threadIdx.x] += t;
        __syncthreads();
    }
    if (i < N) r0[i] = sm[threadIdx.x] - v;
    if (threadIdx.x == 511) bsums[blockIdx.x] = sm[511];
}
__global__ __launch_bounds__(128) void k_scan2f(int* bsums, int nb) {
    __shared__ int sm[128];
    int v = (threadIdx.x < nb) ? bsums[threadIdx.x] : 0;
    sm[threadIdx.x] = v;
    __syncthreads();
    for (int off = 1; off < 128; off <<= 1) {
        int t = (threadIdx.x >= off) ? sm[threadIdx.x - off] : 0;
        __syncthreads();
        sm[threadIdx.x] += t;
        __syncthreads();
    }
    if (threadIdx.x < nb) bsums[threadIdx.x] = sm[threadIdx.x] - v;
}
__global__ __launch_bounds__(512) void k_scan3f(const int* r0, const int* bsums,
                                                int* rowptr, int N, int E) {
    int i = blockIdx.x * 512 + threadIdx.x;
    if (i < N) rowptr[i] = r0[i] + bsums[blockIdx.x];
    if (i == 0) rowptr[N] = E;
}
__global__ __launch_bounds__(256) void k_fill(const int* srcv, const int* dstv,
                                              const int* rowptr, int* deg,
                                              int* adj, int E, int N) {
    int e = blockIdx.x * 256 + threadIdx.x;
    if (e >= E) return;
    int d = dstv[e]; d = min(max(d, 0), N - 1);
    int slot = atomicSub(&deg[d], 1) - 1;
    int idx = rowptr[d] + slot;
    idx = min(max(idx, 0), E - 1);
    adj[idx] = srcv[e];
}

// ---------------- mean aggregation: one wave per node, masked full-ILP -----------
__device__ __forceinline__ void acc8m(uint4 u, float m, float* s) {
    const u32* pu = (const u32*)&u;
#pragma unroll
    for (int t = 0; t < 4; ++t) {
        s[2 * t]     = fmaf(__uint_as_float(pu[t] << 16), m, s[2 * t]);
        s[2 * t + 1] = fmaf(__uint_as_float(pu[t] & 0xffff0000u), m, s[2 * t + 1]);
    }
}

__global__ __launch_bounds__(256) void k_aggregate(const uint4* F, const int* rowptr,
                                                   const int* adj, uint4* A,
                                                   int N, int E) {
    int wid = (int)((blockIdx.x * 256u + threadIdx.x) >> 6);
    int lane = threadIdx.x & 63;
    if (wid >= N) return;
    int beg = rowptr[wid], end = rowptr[wid + 1];
    beg = min(max(beg, 0), E);
    end = min(max(end, beg), E);
    int g = lane >> 4, l = lane & 15;
    float s[8] = {0.f, 0.f, 0.f, 0.f, 0.f, 0.f, 0.f, 0.f};
    for (int j = beg + g; j < end; j += 16) {
        int i1 = j + 4, i2 = j + 8, i3 = j + 12;
        float m1 = (i1 < end) ? 1.f : 0.f;
        float m2 = (i2 < end) ? 1.f : 0.f;
        float m3 = (i3 < end) ? 1.f : 0.f;
        int a0 = min(max(adj[j], 0), N - 1);
        int a1 = min(max(adj[min(i1, end - 1)], 0), N - 1);
        int a2 = min(max(adj[min(i2, end - 1)], 0), N - 1);
        int a3 = min(max(adj[min(i3, end - 1)], 0), N - 1);
        uint4 u0 = F[(size_t)a0 * 16 + l];
        uint4 u1 = F[(size_t)a1 * 16 + l];
        uint4 u2 = F[(size_t)a2 * 16 + l];
        uint4 u3 = F[(size_t)a3 * 16 + l];
        acc8m(u0, 1.f, s);
        acc8m(u1, m1, s);
        acc8m(u2, m2, s);
        acc8m(u3, m3, s);
    }
#pragma unroll
    for (int k = 0; k < 8; ++k) {
        s[k] += __shfl_xor(s[k], 16, 64);
        s[k] += __shfl_xor(s[k], 32, 64);
    }
    if (g == 0) {
        float inv = 1.f / fmaxf((float)(end - beg), 1.f);
        uint4 r; u32* pr = (u32*)&r;
#pragma unroll
        for (int t = 0; t < 4; ++t)
            pr[t] = (u32)f2bf(s[2 * t] * inv) | ((u32)f2bf(s[2 * t + 1] * inv) << 16);
        A[(size_t)wid * 16 + l] = r;
    }
}

// ---------------- layer-1 GEMM: h1 = relu(Agg@Wl^T + b + Xin@Wr^T) ----------------
__global__ __launch_bounds__(256) void k_gemm128(const u16* Agg, const u16* Xin,
                                                 const u32* Wl, const u32* Wr,
                                                 const float* bias, u16* Out, int N) {
    __shared__ __align__(16) u16 Wsh[32768];   // 64 KB -> 2 blocks/CU
    int t = threadIdx.x;
#pragma unroll
    for (int i = 0; i < 16; ++i) {
        int f = i * 256 + t;
        int c = f >> 9, s = (f >> 6) & 7, q = (f >> 4) & 3, n = f & 15;
        int o = c * 16 + n;
        int k = s * 32 + q * 8;
        uint4 v;
        if (k < 128) v = *(const uint4*)(Wl + (size_t)o * 64 + (k >> 1));
        else         v = *(const uint4*)(Wr + (size_t)o * 64 + ((k - 128) >> 1));
        *(uint4*)(Wsh + f * 8) = v;
    }
    __syncthreads();

    int tile = blockIdx.x * 4 + (t >> 6);
    int lane = t & 63;
    int m0 = tile * 16;
    if (m0 >= N) return;
    int mrow = min(m0 + (lane & 15), N - 1);
    int kq = (lane >> 4) * 8;

    bf16x8 afrag[8];
#pragma unroll
    for (int s = 0; s < 8; ++s) {
        int k = s * 32 + kq;
        const u16* p = (k < 128) ? (Agg + (size_t)mrow * 128 + k)
                                 : (Xin + (size_t)mrow * 128 + (k - 128));
        afrag[s] = *(const bf16x8*)p;
    }

    f32x4 acc[8];
#pragma unroll
    for (int c = 0; c < 8; ++c) acc[c] = (f32x4){0.f, 0.f, 0.f, 0.f};

    const u16* lbase = Wsh + (lane >> 4) * 128 + (lane & 15) * 8;
#pragma unroll
    for (int c = 0; c < 8; ++c) {
#pragma unroll
        for (int s = 0; s < 8; ++s) {
            bf16x8 b = *(const bf16x8*)(lbase + (c * 8 + s) * 512);
            acc[c] = __builtin_amdgcn_mfma_f32_16x16x32_bf16(afrag[s], b, acc[c], 0, 0, 0);
        }
    }

#pragma unroll
    for (int c = 0; c < 8; ++c) {
        int o = c * 16 + (lane & 15);
        float bv = bias[o];
#pragma unroll
        for (int r = 0; r < 4; ++r) {
            int m = m0 + (lane >> 4) * 4 + r;
            float v = acc[c][r] + bv;
            v = fmaxf(v, 0.f);   // relu
            if (m < N) Out[(size_t)m * 128 + o] = f2bf(v);
        }
    }
}

// ---------------- layer-2 GEMM + elu + fused layer-3 head (butterfly) -------------
// h2 stays in registers (C-layout row=quad*4+r, col=c*16+k15). Head: per r,
// partials pj[8]/qj[8] over c, then a segmented butterfly over the quad's 16
// lanes (4+2+1 value-halving xor steps + 1 full add) = 16 shfls/r (64 total,
// vs 256 for the naive all-reduce). Lane k15 ends with j = 4*b0+2*b1+b2;
// lanes 0-7 store Y, 8-15 store R. Mapping HW-verified in r12 run.
__global__ __launch_bounds__(256) void k_gemm2(const u16* Agg, const u16* Xin,
                                               const u32* Wl, const u32* Wr,
                                               const float* bias,
                                               const u32* W2l, const u32* W2r,
                                               const float* b2,
                                               float* Y, float* R, int N) {
    __shared__ __align__(16) u16 Wsh[32768];   // 64 KB
    __shared__ float W2sh[2048];               // +8 KB: W2l,W2r as f32
    int t = threadIdx.x;
#pragma unroll
    for (int i = 0; i < 16; ++i) {
        int f = i * 256 + t;
        int c = f >> 9, s = (f >> 6) & 7, q = (f >> 4) & 3, n = f & 15;
        int o = c * 16 + n;
        int k = s * 32 + q * 8;
        uint4 v;
        if (k < 128) v = *(const uint4*)(Wl + (size_t)o * 64 + (k >> 1));
        else         v = *(const uint4*)(Wr + (size_t)o * 64 + ((k - 128) >> 1));
        *(uint4*)(Wsh + f * 8) = v;
    }
#pragma unroll
    for (int i = t; i < 512; i += 256) {
        u32 wa = W2l[i], wb = W2r[i];
        W2sh[2 * i]            = bf2f((u16)(wa & 0xffffu));
        W2sh[2 * i + 1]        = bf2f((u16)(wa >> 16));
        W2sh[1024 + 2 * i]     = bf2f((u16)(wb & 0xffffu));
        W2sh[1024 + 2 * i + 1] = bf2f((u16)(wb >> 16));
    }
    __syncthreads();

    int tile = blockIdx.x * 4 + (t >> 6);
    int lane = t & 63;
    int m0 = tile * 16;
    if (m0 >= N) return;
    int mrow = min(m0 + (lane & 15), N - 1);
    int kq = (lane >> 4) * 8;

    bf16x8 afrag[8];
#pragma unroll
    for (int s = 0; s < 8; ++s) {
        int k = s * 32 + kq;
        const u16* p = (k < 128) ? (Agg + (size_t)mrow * 128 + k)
                                 : (Xin + (size_t)mrow * 128 + (k - 128));
        afrag[s] = *(const bf16x8*)p;
    }

    f32x4 acc[8];
#pragma unroll
    for (int c = 0; c < 8; ++c) acc[c] = (f32x4){0.f, 0.f, 0.f, 0.f};

    const u16* lbase = Wsh + (lane >> 4) * 128 + (lane & 15) * 8;
#pragma unroll
    for (int c = 0; c < 8; ++c) {
#pragma unroll
        for (int s = 0; s < 8; ++s) {
            bf16x8 b = *(const bf16x8*)(lbase + (c * 8 + s) * 512);
            acc[c] = __builtin_amdgcn_mfma_f32_16x16x32_bf16(afrag[s], b, acc[c], 0, 0, 0);
        }
    }

    int quad = lane >> 4, k15 = lane & 15;
#pragma unroll
    for (int c = 0; c < 8; ++c) {
        float bv = bias[c * 16 + k15];
#pragma unroll
        for (int r = 0; r < 4; ++r) {
            float v = acc[c][r] + bv;
            acc[c][r] = (v > 0.f) ? v : expm1f(v);   // elu
        }
    }

    bool b0 = (k15 & 1) != 0, b1 = (k15 & 2) != 0, b2v = (k15 & 4) != 0;
    int jm = 4 * (k15 & 1) + (k15 & 2) + ((k15 >> 2) & 1);
#pragma unroll
    for (int r = 0; r < 4; ++r) {
        float pj[8], qj[8];
#pragma unroll
        for (int j = 0; j < 8; ++j) { pj[j] = 0.f; qj[j] = 0.f; }
#pragma unroll
        for (int c = 0; c < 8; ++c) {
            float av = acc[c][r];
#pragma unroll
            for (int j = 0; j < 8; ++j) {
                pj[j] = fmaf(av, W2sh[j * 128 + c * 16 + k15], pj[j]);
                qj[j] = fmaf(av, W2sh[1024 + j * 128 + c * 16 + k15], qj[j]);
            }
        }
        // butterfly: xor1 (keep 4), xor2 (keep 2), xor4 (keep 1), xor8 (full add)
        float p4[4], q4[4];
#pragma unroll
        for (int j = 0; j < 4; ++j) {
            float ps = b0 ? pj[j] : pj[j + 4];
            float qs = b0 ? qj[j] : qj[j + 4];
            p4[j] = (b0 ? pj[j + 4] : pj[j]) + __shfl_xor(ps, 1, 64);
            q4[j] = (b0 ? qj[j + 4] : qj[j]) + __shfl_xor(qs, 1, 64);
        }
        float p2[2], q2[2];
#pragma unroll
        for (int j = 0; j < 2; ++j) {
            float ps = b1 ? p4[j] : p4[j + 2];
            float qs = b1 ? q4[j] : q4[j + 2];
            p2[j] = (b1 ? p4[j + 2] : p4[j]) + __shfl_xor(ps, 2, 64);
            q2[j] = (b1 ? q4[j + 2] : q4[j]) + __shfl_xor(qs, 2, 64);
        }
        float ps = b2v ? p2[0] : p2[1];
        float qs = b2v ? q2[0] : q2[1];
        float pv = (b2v ? p2[1] : p2[0]) + __shfl_xor(ps, 4, 64);
        float qv = (b2v ? q2[1] : q2[0]) + __shfl_xor(qs, 4, 64);
        pv += __shfl_xor(pv, 8, 64);
        qv += __shfl_xor(qv, 8, 64);
        int m = m0 + quad * 4 + r;
        if (m < N) {
            if (k15 < 8) Y[(size_t)m * 8 + jm] = pv;
            else         R[(size_t)m * 8 + jm] = qv + b2[jm];
        }
    }
}

// ---------------- final: mean-aggregate Y + R + log_softmax ----------------------
__global__ __launch_bounds__(256) void k_agg8sm(const float* Y, const float* R,
                                                const int* rowptr, const int* adj,
                                                const int* flag, void* Out,
                                                int N, int E) {
    int t = blockIdx.x * 256 + threadIdx.x;
    int n = t >> 3;
    int o = t & 7;
    if (n >= N) return;
    int beg = rowptr[n], end = rowptr[n + 1];
    beg = min(max(beg, 0), E);
    end = min(max(end, beg), E);
    float s = 0.f;
    int j = beg;
    for (; j + 1 < end; j += 2) {
        int a0 = min(max(adj[j], 0), N - 1);
        int a1 = min(max(adj[j + 1], 0), N - 1);
        s += Y[(size_t)a0 * 8 + o];
        s += Y[(size_t)a1 * 8 + o];
    }
    if (j < end) {
        int a0 = min(max(adj[j], 0), N - 1);
        s += Y[(size_t)a0 * 8 + o];
    }
    float acc = s / fmaxf((float)(end - beg), 1.f) + R[(size_t)n * 8 + o];
    float mx = acc;
#pragma unroll
    for (int d = 1; d < 8; d <<= 1) mx = fmaxf(mx, __shfl_xor(mx, d, 64));
    float ex = expf(acc - mx), se = ex;
#pragma unroll
    for (int d = 1; d < 8; d <<= 1) se += __shfl_xor(se, d, 64);
    float v = acc - mx - logf(se);
    if (*flag) ((float*)Out)[(size_t)n * 8 + o] = v;
    else       ((u16*)Out)[(size_t)n * 8 + o] = f2bf(v);
}

// ---------------- launch ----------------
extern "C" void kernel_launch(void* const* d_in, const int* in_sizes, int n_in,
                              void* d_out, int out_size, void* d_ws, size_t ws_size,
                              hipStream_t stream) {
    const void* x   = d_in[0];
    const int* ei   = (const int*)d_in[1];
    const int N = in_sizes[0] / 128;
    const int E = in_sizes[1] / 2;
    const int* srcv = ei;
    const int* dstv = ei + E;
    const int NBUK = (N + 255) >> 8;         // buckets of 256 nodes
    const int bucketed = (NBUK <= 256) ? 1 : 0;
    const int chunk = (E + NCB - 1) / NCB;
    const int cvtB = (N * 16 + 255) / 256;
    const int nbA = (N + 511) / 512;

    auto rnd = [](size_t b) { return (b + 255) & ~(size_t)255; };
    size_t need = rnd(256)                    // flag
                + rnd((size_t)N * 4)          // deg (fallback)
                + rnd((size_t)N * 4)          // r0 (fallback)
                + rnd((size_t)(N + 1) * 4)    // rowptr
                + rnd(4096)                   // bsums (fallback)
                + rnd(256 * NCB * 4)          // C matrix
                + rnd(1024) + rnd(1024)       // T, B
                + rnd((size_t)E * 4)          // adj
                + 2 * rnd((size_t)N * 256)    // X, A
                + 2 * rnd((size_t)N * 32)     // Y, R
                + 4 * rnd(32768) + 2 * rnd(2048) + 2 * rnd(512) + rnd(64);
    if (ws_size < need) {
        k_sentinel<<<(out_size + 255) / 256, 256, 0, stream>>>((u16*)d_out, out_size);
        return;
    }

    char* p = (char*)d_ws;
    auto carve = [&](size_t bytes) { char* r = p; p += (bytes + 255) & ~(size_t)255; return r; };
    int* flag   = (int*)carve(256);
    int* deg    = (int*)carve((size_t)N * 4);
    int* r0     = (int*)carve((size_t)N * 4);
    int* rowptr = (int*)carve((size_t)(N + 1) * 4);
    int* bsums  = (int*)carve(4096);
    int* C      = (int*)carve(256 * NCB * 4);
    int* T      = (int*)carve(1024);
    int* B      = (int*)carve(1024);
    int* adj    = (int*)carve((size_t)E * 4);
    u32* X      = (u32*)carve((size_t)N * 256);   // [N,128] packed bf16
    u32* A      = (u32*)carve((size_t)N * 256);   // agg buffer
    float* Y    = (float*)carve((size_t)N * 32);  // [N,8] f32
    float* R    = (float*)carve((size_t)N * 32);
    u32* w1l = (u32*)carve(32768); u32* w1r = (u32*)carve(32768);
    u32* whl = (u32*)carve(32768); u32* whr = (u32*)carve(32768);
    u32* w2l = (u32*)carve(2048);  u32* w2r = (u32*)carve(2048);
    float* bf1 = (float*)carve(512); float* bfh = (float*)carve(512);
    float* bf2 = (float*)carve(64);
    u32* pairs = A;                  // consumed by k_fillb2 before first aggregate
    (void)n_in;

    // 1: dtype detect
    k_detect<<<1, 64, 0, stream>>>((const u32*)x, flag);
    // 2: convert x + params + bucket count (LDS-only atomics)
    k_front<<<cvtB + 134 + (bucketed ? 256 : 0), 256, 0, stream>>>(
        x, dstv, flag, bucketed, (uint4*)X, C, E, N, chunk, cvtB,
        d_in[3], d_in[5], d_in[6], d_in[8], d_in[9], d_in[11],
        d_in[4], d_in[7], d_in[10],
        w1l, w1r, whl, whr, w2l, w2r, bf1, bfh, bf2);
    if (bucketed) {
        k_scanT<<<NBUK, 256, 0, stream>>>(C, T);
        k_scanB<<<1, 256, 0, stream>>>(T, B, NBUK);
        k_place<<<NCB, 256, 0, stream>>>(srcv, dstv, C, B, pairs, E, N, chunk);
        k_fillb2<<<NBUK, 256, 0, stream>>>(pairs, B, T, rowptr, adj, E, N, NBUK);
    } else {
        k_zero<<<(N + 255) / 256, 256, 0, stream>>>(deg, N);
        k_deg<<<(E + 255) / 256, 256, 0, stream>>>(dstv, deg, E, N);
        k_scan1<<<nbA, 512, 0, stream>>>(deg, r0, bsums, N);
        k_scan2f<<<1, 128, 0, stream>>>(bsums, nbA);
        k_scan3f<<<nbA, 512, 0, stream>>>(r0, bsums, rowptr, N, E);
        k_fill<<<(E + 255) / 256, 256, 0, stream>>>(srcv, dstv, rowptr, deg, adj, E, N);
    }

    int aggBlocks = (int)(((size_t)N * 64 + 255) / 256);
    int gemmBlocks = ((N + 15) / 16 + 3) / 4;
    int perNode8 = (int)(((size_t)N * 8 + 255) / 256);

    // L1: A=mean(X); h1=relu(A@W1l^T+b1+X@W1r^T) -> X (own-rows aliasing, safe)
    k_aggregate<<<aggBlocks, 256, 0, stream>>>((const uint4*)X, rowptr, adj, (uint4*)A, N, E);
    k_gemm128<<<gemmBlocks, 256, 0, stream>>>((const u16*)A, (const u16*)X, w1l, w1r, bf1, (u16*)X, N);
    // L2: A=mean(h1); fused gemm+elu+head -> Y,R (h2 never materialized)
    k_aggregate<<<aggBlocks, 256, 0, stream>>>((const uint4*)X, rowptr, adj, (uint4*)A, N, E);
    k_gemm2<<<gemmBlocks, 256, 0, stream>>>((const u16*)A, (const u16*)X, whl, whr, bfh,
                                            w2l, w2r, bf2, Y, R, N);
    // out = log_softmax(mean_agg(Y) + R)
    k_agg8sm<<<perNode8, 256, 0, stream>>>(Y, R, rowptr, adj, flag, d_out, N, E);
}

// Round 14
// 225.591 us; speedup vs baseline: 2.3467x; 1.0839x over previous
//
#include <hip/hip_runtime.h>

typedef unsigned int u32;
typedef unsigned short u16;
typedef short bf16x8 __attribute__((ext_vector_type(8)));   // 8 bf16 (4 VGPRs)
typedef float f32x4 __attribute__((ext_vector_type(4)));    // MFMA accumulator

#define NCB 256   // blocks for count/place passes (fixed)

__device__ __forceinline__ float bf2f(u16 h) { return __uint_as_float(((u32)h) << 16); }
__device__ __forceinline__ u16 f2bf(float f) {
    u32 u = __float_as_uint(f);
    return (u16)((u + 0x7fffu + ((u >> 16) & 1u)) >> 16);   // RNE
}

// ---------------- diagnostic fallback: ws too small ----------------
__global__ __launch_bounds__(256) void k_sentinel(u16* out, int n) {
    int i = blockIdx.x * 256 + threadIdx.x;
    if (i < n) out[i] = f2bf(-7.0f);
}

// ---------------- front: x-convert + param-convert + bucket count -----------------
// Every block computes the dtype flag locally (1KB broadcast read, ~free);
// block 0 publishes it for k_agg8sm (dispatch-boundary coherence).
__global__ __launch_bounds__(256) void k_front(
    const void* x, const int* dstv, int* flagOut, int bucketed,
    uint4* X, int* C, int E, int N, int chunk, int cvtB,
    const void* s1l, const void* s1r, const void* shl, const void* shr,
    const void* s2l, const void* s2r, const void* sb1, const void* sbh,
    const void* sb2,
    u32* w1l, u32* w1r, u32* whl, u32* whr, u32* w2l, u32* w2r,
    float* bf1, float* bfh, float* bf2) {
    __shared__ int hist[256];
    __shared__ int sflag;
    int b = blockIdx.x, t = threadIdx.x;
    // inline dtype detect (flag=0 bf16-packed, 1 f32)
    if (t < 64) {
        int c = 0;
        for (int j = 0; j < 4; ++j) {
            u32 u = ((const u32*)x)[t * 4 + j];
            u32 e = (u >> 7) & 0xffu;
            if ((e >= 0x30u && e <= 0x47u) || ((u & 0x7fffu) == 0u)) ++c;
        }
        for (int d = 32; d; d >>= 1) c += __shfl_down(c, d, 64);
        if (t == 0) sflag = (c < 128) ? 1 : 0;
    }
    __syncthreads();
    int fl = sflag;
    if (b == 0 && t == 0) *flagOut = fl;

    if (b < cvtB) {
        int i = b * 256 + t;
        if (i >= N * 16) return;
        if (fl) {
            const float4* s = (const float4*)x;
            float4 a = s[2 * i], c4 = s[2 * i + 1];
            uint4 o;
            o.x = (u32)f2bf(a.x) | ((u32)f2bf(a.y) << 16);
            o.y = (u32)f2bf(a.z) | ((u32)f2bf(a.w) << 16);
            o.z = (u32)f2bf(c4.x) | ((u32)f2bf(c4.y) << 16);
            o.w = (u32)f2bf(c4.z) | ((u32)f2bf(c4.w) << 16);
            X[i] = o;
        } else {
            X[i] = ((const uint4*)x)[i];
        }
    } else if (b < cvtB + 134) {
        int bb = b - cvtB;
        auto cv = [&](const void* src, u32* dst, int base) {
            int i = base + t;
            if (fl) {
                const float* s = (const float*)src;
                dst[i] = (u32)f2bf(s[2 * i]) | ((u32)f2bf(s[2 * i + 1]) << 16);
            } else {
                dst[i] = ((const u32*)src)[i];
            }
        };
        auto cb = [&](const void* src, float* dst, int i) {
            dst[i] = fl ? ((const float*)src)[i] : bf2f(((const u16*)src)[i]);
        };
        if      (bb <  32) cv(s1l, w1l, bb * 256);
        else if (bb <  64) cv(s1r, w1r, (bb - 32) * 256);
        else if (bb <  96) cv(shl, whl, (bb - 64) * 256);
        else if (bb < 128) cv(shr, whr, (bb - 96) * 256);
        else if (bb < 130) cv(s2l, w2l, (bb - 128) * 256);
        else if (bb < 132) cv(s2r, w2r, (bb - 130) * 256);
        else if (bb == 132) {
            if (t < 128) cb(sb1, bf1, t);
            else         cb(sbh, bfh, t - 128);
        } else {
            if (t < 8) cb(sb2, bf2, t);
        }
    } else if (bucketed) {
        int cb2 = b - cvtB - 134;    // count block 0..255
        hist[t] = 0;
        __syncthreads();
        int e0 = cb2 * chunk;
        int e1 = min(e0 + chunk, E);
        for (int e = e0 + t; e < e1; e += 256) {
            int d = min(max(dstv[e], 0), N - 1);
            atomicAdd(&hist[d >> 8], 1);   // LDS only
        }
        __syncthreads();
        C[cb2 * 256 + t] = hist[t];        // transposed: coalesced write
    }
}

// ---------------- per-bucket: exclusive scan of C over blocks + total -------------
__global__ __launch_bounds__(256) void k_scanT(int* C, int* T) {
    __shared__ int sm[256];
    int bu = blockIdx.x, t = threadIdx.x;
    int v = C[t * 256 + bu];
    sm[t] = v;
    __syncthreads();
    for (int off = 1; off < 256; off <<= 1) {
        int u = (t >= off) ? sm[t - off] : 0;
        __syncthreads();
        sm[t] += u;
        __syncthreads();
    }
    C[t * 256 + bu] = sm[t] - v;       // block-prefix within bucket
    if (t == 255) T[bu] = sm[255];     // bucket total
}

// ---------------- exclusive scan of bucket totals -> bucket bases -----------------
__global__ __launch_bounds__(256) void k_scanB(const int* T, int* B, int nbuk) {
    __shared__ int sm[256];
    int t = threadIdx.x;
    int v = (t < nbuk) ? T[t] : 0;
    sm[t] = v;
    __syncthreads();
    for (int off = 1; off < 256; off <<= 1) {
        int u = (t >= off) ? sm[t - off] : 0;
        __syncthreads();
        sm[t] += u;
        __syncthreads();
    }
    B[t] = sm[t] - v;
}

// ---------------- place edges into bucket-segmented pairs ----------------
__global__ __launch_bounds__(256) void k_place(const int* srcv, const int* dstv,
                                               const int* C, const int* Bb,
                                               u32* pairs, int E, int N, int chunk) {
    __shared__ int base[256], cnt[256];
    int t = threadIdx.x;
    base[t] = Bb[t] + C[blockIdx.x * 256 + t];
    cnt[t] = 0;
    __syncthreads();
    int e0 = blockIdx.x * chunk;
    int e1 = min(e0 + chunk, E);
    for (int e = e0 + t; e < e1; e += 256) {
        int d = min(max(dstv[e], 0), N - 1);
        int s = min(max(srcv[e], 0), N - 1);
        int b = d >> 8;
        int pos = base[b] + atomicAdd(&cnt[b], 1);
        pos = min(max(pos, 0), E - 1);
        pairs[pos] = ((u32)s << 8) | (u32)(d & 255);
    }
}

// ---------------- per-bucket: local degree count + scan -> rowptr; scatter adj ----
__global__ __launch_bounds__(256) void k_fillb2(const u32* pairs, const int* Bb,
                                                const int* T, int* rowptr,
                                                int* adj, int E, int N, int nbuk) {
    int bu = blockIdx.x;
    int n0 = bu << 8;
    int nn = min(N - n0, 256);
    __shared__ int dcnt[256], sm[256], cur[256];
    int t = threadIdx.x;
    dcnt[t] = 0;
    __syncthreads();
    int s0 = min(max(Bb[bu], 0), E);
    int s1 = min(s0 + max(T[bu], 0), E);
    for (int e = s0 + t; e < s1; e += 256) {
        int ld = (int)(pairs[e] & 255u);
        atomicAdd(&dcnt[min(ld, nn - 1)], 1);
    }
    __syncthreads();
    int v = dcnt[t];
    sm[t] = v;
    __syncthreads();
    for (int off = 1; off < 256; off <<= 1) {
        int u = (t >= off) ? sm[t - off] : 0;
        __syncthreads();
        sm[t] += u;
        __syncthreads();
    }
    int excl = sm[t] - v;
    cur[t] = excl;
    if (t < nn) rowptr[n0 + t] = s0 + excl;
    if (bu == nbuk - 1 && t == 0) rowptr[N] = E;
    __syncthreads();
    for (int e = s0 + t; e < s1; e += 256) {
        u32 pc = pairs[e];
        int ld = min((int)(pc & 255u), nn - 1);
        int src = (int)(pc >> 8);
        int slot = atomicAdd(&cur[ld], 1);
        int idx = min(max(s0 + slot, 0), E - 1);
        adj[idx] = src;
    }
}

// ---------------- fallback CSR for N > 65536 (global atomics path) ----------------
__global__ __launch_bounds__(256) void k_zero(int* deg, int N) {
    int i = blockIdx.x * 256 + threadIdx.x;
    if (i < N) deg[i] = 0;
}
__global__ __launch_bounds__(256) void k_deg(const int* dstv, int* deg, int E, int N) {
    int e = blockIdx.x * 256 + threadIdx.x;
    if (e >= E) return;
    int d = dstv[e]; d = min(max(d, 0), N - 1);
    atomicAdd(&deg[d], 1);
}
__global__ __launch_bounds__(512) void k_scan1(const int* deg, int* r0,
                                               int* bsums, int N) {
    __shared__ int sm[512];
    int i = blockIdx.x * 512 + threadIdx.x;
    int v = (i < N) ? deg[i] : 0;
    sm[threadIdx.x] = v;
    __syncthreads();
    for (int off = 1; off < 512; off <<= 1) {
        int t = (threadIdx.x >= off) ? sm[threadIdx.x - off] : 0;
        __syncthreads();
        sm[threadIdx.x] += t;
        __syncthreads();
    }
    if (i < N) r0[i] = sm[threadIdx.x] - v;
    if (threadIdx.x == 511) bsums[blockIdx.x] = sm[511];
}
__global__ __launch_bounds__(128) void k_scan2f(int* bsums, int nb) {
    __shared__ int sm[128];
    int v = (threadIdx.x < nb) ? bsums[threadIdx.x] : 0;
    sm[threadIdx.x] = v;
    __syncthreads();
    for (int off = 1; off < 128; off <<= 1) {
        int t = (threadIdx.x >= off) ? sm[threadIdx.x - off] : 0;
        __syncthreads();
        sm[threadIdx.x] += t;
        __syncthreads();
    }
    if (threadIdx.x < nb) bsums[threadIdx.x] = sm[threadIdx.x] - v;
}
__global__ __launch_bounds__(512) void k_scan3f(const int* r0, const int* bsums,
                                                int* rowptr, int N, int E) {
    int i = blockIdx.x * 512 + threadIdx.x;
    if (i < N) rowptr[i] = r0[i] + bsums[blockIdx.x];
    if (i == 0) rowptr[N] = E;
}
__global__ __launch_bounds__(256) void k_fill(const int* srcv, const int* dstv,
                                              const int* rowptr, int* deg,
                                              int* adj, int E, int N) {
    int e = blockIdx.x * 256 + threadIdx.x;
    if (e >= E) return;
    int d = dstv[e]; d = min(max(d, 0), N - 1);
    int slot = atomicSub(&deg[d], 1) - 1;
    int idx = rowptr[d] + slot;
    idx = min(max(idx, 0), E - 1);
    adj[idx] = srcv[e];
}

// ---------------- mean aggregation: one wave per node, masked full-ILP -----------
__device__ __forceinline__ void acc8m(uint4 u, float m, float* s) {
    const u32* pu = (const u32*)&u;
#pragma unroll
    for (int t = 0; t < 4; ++t) {
        s[2 * t]     = fmaf(__uint_as_float(pu[t] << 16), m, s[2 * t]);
        s[2 * t + 1] = fmaf(__uint_as_float(pu[t] & 0xffff0000u), m, s[2 * t + 1]);
    }
}

__global__ __launch_bounds__(256) void k_aggregate(const uint4* F, const int* rowptr,
                                                   const int* adj, uint4* A,
                                                   int N, int E) {
    int wid = (int)((blockIdx.x * 256u + threadIdx.x) >> 6);
    int lane = threadIdx.x & 63;
    if (wid >= N) return;
    int beg = rowptr[wid], end = rowptr[wid + 1];
    beg = min(max(beg, 0), E);
    end = min(max(end, beg), E);
    int g = lane >> 4, l = lane & 15;
    float s[8] = {0.f, 0.f, 0.f, 0.f, 0.f, 0.f, 0.f, 0.f};
    for (int j = beg + g; j < end; j += 16) {
        int i1 = j + 4, i2 = j + 8, i3 = j + 12;
        float m1 = (i1 < end) ? 1.f : 0.f;
        float m2 = (i2 < end) ? 1.f : 0.f;
        float m3 = (i3 < end) ? 1.f : 0.f;
        int a0 = min(max(adj[j], 0), N - 1);
        int a1 = min(max(adj[min(i1, end - 1)], 0), N - 1);
        int a2 = min(max(adj[min(i2, end - 1)], 0), N - 1);
        int a3 = min(max(adj[min(i3, end - 1)], 0), N - 1);
        uint4 u0 = F[(size_t)a0 * 16 + l];
        uint4 u1 = F[(size_t)a1 * 16 + l];
        uint4 u2 = F[(size_t)a2 * 16 + l];
        uint4 u3 = F[(size_t)a3 * 16 + l];
        acc8m(u0, 1.f, s);
        acc8m(u1, m1, s);
        acc8m(u2, m2, s);
        acc8m(u3, m3, s);
    }
#pragma unroll
    for (int k = 0; k < 8; ++k) {
        s[k] += __shfl_xor(s[k], 16, 64);
        s[k] += __shfl_xor(s[k], 32, 64);
    }
    if (g == 0) {
        float inv = 1.f / fmaxf((float)(end - beg), 1.f);
        uint4 r; u32* pr = (u32*)&r;
#pragma unroll
        for (int t = 0; t < 4; ++t)
            pr[t] = (u32)f2bf(s[2 * t] * inv) | ((u32)f2bf(s[2 * t + 1] * inv) << 16);
        A[(size_t)wid * 16 + l] = r;
    }
}

// ---------------- layer-1 GEMM: h1 = relu(Agg@Wl^T + b + Xin@Wr^T) ----------------
// 512 threads = 8 waves/block, one 16-row tile each; 64 KB LDS -> 2 blocks/CU
// = 16 waves/CU (2x A-gather concurrency vs 256-thread blocks) and half the
// total weight-staging traffic.
__global__ __launch_bounds__(512) void k_gemm128(const u16* Agg, const u16* Xin,
                                                 const u32* Wl, const u32* Wr,
                                                 const float* bias, u16* Out, int N) {
    __shared__ __align__(16) u16 Wsh[32768];   // 64 KB
    int t = threadIdx.x;
#pragma unroll
    for (int i = 0; i < 8; ++i) {
        int f = i * 512 + t;
        int c = f >> 9, s = (f >> 6) & 7, q = (f >> 4) & 3, n = f & 15;
        int o = c * 16 + n;
        int k = s * 32 + q * 8;
        uint4 v;
        if (k < 128) v = *(const uint4*)(Wl + (size_t)o * 64 + (k >> 1));
        else         v = *(const uint4*)(Wr + (size_t)o * 64 + ((k - 128) >> 1));
        *(uint4*)(Wsh + f * 8) = v;
    }
    __syncthreads();

    int tile = blockIdx.x * 8 + (t >> 6);
    int lane = t & 63;
    int m0 = tile * 16;
    if (m0 >= N) return;
    int mrow = min(m0 + (lane & 15), N - 1);
    int kq = (lane >> 4) * 8;

    bf16x8 afrag[8];
#pragma unroll
    for (int s = 0; s < 8; ++s) {
        int k = s * 32 + kq;
        const u16* p = (k < 128) ? (Agg + (size_t)mrow * 128 + k)
                                 : (Xin + (size_t)mrow * 128 + (k - 128));
        afrag[s] = *(const bf16x8*)p;
    }

    f32x4 acc[8];
#pragma unroll
    for (int c = 0; c < 8; ++c) acc[c] = (f32x4){0.f, 0.f, 0.f, 0.f};

    const u16* lbase = Wsh + (lane >> 4) * 128 + (lane & 15) * 8;
#pragma unroll
    for (int c = 0; c < 8; ++c) {
#pragma unroll
        for (int s = 0; s < 8; ++s) {
            bf16x8 b = *(const bf16x8*)(lbase + (c * 8 + s) * 512);
            acc[c] = __builtin_amdgcn_mfma_f32_16x16x32_bf16(afrag[s], b, acc[c], 0, 0, 0);
        }
    }

#pragma unroll
    for (int c = 0; c < 8; ++c) {
        int o = c * 16 + (lane & 15);
        float bv = bias[o];
#pragma unroll
        for (int r = 0; r < 4; ++r) {
            int m = m0 + (lane >> 4) * 4 + r;
            float v = acc[c][r] + bv;
            v = fmaxf(v, 0.f);   // relu
            if (m < N) Out[(size_t)m * 128 + o] = f2bf(v);
        }
    }
}

// ---------------- layer-2 GEMM + elu + fused layer-3 head (butterfly) -------------
// 512 threads, 72 KB LDS -> 2 blocks/CU = 16 waves/CU. Head: segmented
// butterfly (4+2+1 value-halving xor steps + 1 full add) = 64 shfls total.
__global__ __launch_bounds__(512) void k_gemm2(const u16* Agg, const u16* Xin,
                                               const u32* Wl, const u32* Wr,
                                               const float* bias,
                                               const u32* W2l, const u32* W2r,
                                               const float* b2,
                                               float* Y, float* R, int N) {
    __shared__ __align__(16) u16 Wsh[32768];   // 64 KB
    __shared__ float W2sh[2048];               // +8 KB: W2l,W2r as f32
    int t = threadIdx.x;
#pragma unroll
    for (int i = 0; i < 8; ++i) {
        int f = i * 512 + t;
        int c = f >> 9, s = (f >> 6) & 7, q = (f >> 4) & 3, n = f & 15;
        int o = c * 16 + n;
        int k = s * 32 + q * 8;
        uint4 v;
        if (k < 128) v = *(const uint4*)(Wl + (size_t)o * 64 + (k >> 1));
        else         v = *(const uint4*)(Wr + (size_t)o * 64 + ((k - 128) >> 1));
        *(uint4*)(Wsh + f * 8) = v;
    }
    if (t < 512) {
        u32 wa = W2l[t], wb = W2r[t];
        W2sh[2 * t]            = bf2f((u16)(wa & 0xffffu));
        W2sh[2 * t + 1]        = bf2f((u16)(wa >> 16));
        W2sh[1024 + 2 * t]     = bf2f((u16)(wb & 0xffffu));
        W2sh[1024 + 2 * t + 1] = bf2f((u16)(wb >> 16));
    }
    __syncthreads();

    int tile = blockIdx.x * 8 + (t >> 6);
    int lane = t & 63;
    int m0 = tile * 16;
    if (m0 >= N) return;
    int mrow = min(m0 + (lane & 15), N - 1);
    int kq = (lane >> 4) * 8;

    bf16x8 afrag[8];
#pragma unroll
    for (int s = 0; s < 8; ++s) {
        int k = s * 32 + kq;
        const u16* p = (k < 128) ? (Agg + (size_t)mrow * 128 + k)
                                 : (Xin + (size_t)mrow * 128 + (k - 128));
        afrag[s] = *(const bf16x8*)p;
    }

    f32x4 acc[8];
#pragma unroll
    for (int c = 0; c < 8; ++c) acc[c] = (f32x4){0.f, 0.f, 0.f, 0.f};

    const u16* lbase = Wsh + (lane >> 4) * 128 + (lane & 15) * 8;
#pragma unroll
    for (int c = 0; c < 8; ++c) {
#pragma unroll
        for (int s = 0; s < 8; ++s) {
            bf16x8 b = *(const bf16x8*)(lbase + (c * 8 + s) * 512);
            acc[c] = __builtin_amdgcn_mfma_f32_16x16x32_bf16(afrag[s], b, acc[c], 0, 0, 0);
        }
    }

    int quad = lane >> 4, k15 = lane & 15;
#pragma unroll
    for (int c = 0; c < 8; ++c) {
        float bv = bias[c * 16 + k15];
#pragma unroll
        for (int r = 0; r < 4; ++r) {
            float v = acc[c][r] + bv;
            acc[c][r] = (v > 0.f) ? v : expm1f(v);   // elu
        }
    }

    bool b0 = (k15 & 1) != 0, b1 = (k15 & 2) != 0, b2v = (k15 & 4) != 0;
    int jm = 4 * (k15 & 1) + (k15 & 2) + ((k15 >> 2) & 1);
#pragma unroll
    for (int r = 0; r < 4; ++r) {
        float pj[8], qj[8];
#pragma unroll
        for (int j = 0; j < 8; ++j) { pj[j] = 0.f; qj[j] = 0.f; }
#pragma unroll
        for (int c = 0; c < 8; ++c) {
            float av = acc[c][r];
#pragma unroll
            for (int j = 0; j < 8; ++j) {
                pj[j] = fmaf(av, W2sh[j * 128 + c * 16 + k15], pj[j]);
                qj[j] = fmaf(av, W2sh[1024 + j * 128 + c * 16 + k15], qj[j]);
            }
        }
        float p4[4], q4[4];
#pragma unroll
        for (int j = 0; j < 4; ++j) {
            float ps = b0 ? pj[j] : pj[j + 4];
            float qs = b0 ? qj[j] : qj[j + 4];
            p4[j] = (b0 ? pj[j + 4] : pj[j]) + __shfl_xor(ps, 1, 64);
            q4[j] = (b0 ? qj[j + 4] : qj[j]) + __shfl_xor(qs, 1, 64);
        }
        float p2[2], q2[2];
#pragma unroll
        for (int j = 0; j < 2; ++j) {
            float ps = b1 ? p4[j] : p4[j + 2];
            float qs = b1 ? q4[j] : q4[j + 2];
            p2[j] = (b1 ? p4[j + 2] : p4[j]) + __shfl_xor(ps, 2, 64);
            q2[j] = (b1 ? q4[j + 2] : q4[j]) + __shfl_xor(qs, 2, 64);
        }
        float ps = b2v ? p2[0] : p2[1];
        float qs = b2v ? q2[0] : q2[1];
        float pv = (b2v ? p2[1] : p2[0]) + __shfl_xor(ps, 4, 64);
        float qv = (b2v ? q2[1] : q2[0]) + __shfl_xor(qs, 4, 64);
        pv += __shfl_xor(pv, 8, 64);
        qv += __shfl_xor(qv, 8, 64);
        int m = m0 + quad * 4 + r;
        if (m < N) {
            if (k15 < 8) Y[(size_t)m * 8 + jm] = pv;
            else         R[(size_t)m * 8 + jm] = qv + b2[jm];
        }
    }
}

// ---------------- final: mean-aggregate Y + R + log_softmax (masked unroll-4) ----
__global__ __launch_bounds__(256) void k_agg8sm(const float* Y, const float* R,
                                                const int* rowptr, const int* adj,
                                                const int* flag, void* Out,
                                                int N, int E) {
    int t = blockIdx.x * 256 + threadIdx.x;
    int n = t >> 3;
    int o = t & 7;
    if (n >= N) return;
    int beg = rowptr[n], end = rowptr[n + 1];
    beg = min(max(beg, 0), E);
    end = min(max(end, beg), E);
    float s = 0.f;
    for (int j = beg; j < end; j += 4) {
        int j1 = j + 1, j2 = j + 2, j3 = j + 3;
        float m1 = (j1 < end) ? 1.f : 0.f;
        float m2 = (j2 < end) ? 1.f : 0.f;
        float m3 = (j3 < end) ? 1.f : 0.f;
        int a0 = min(max(adj[j], 0), N - 1);
        int a1 = min(max(adj[min(j1, end - 1)], 0), N - 1);
        int a2 = min(max(adj[min(j2, end - 1)], 0), N - 1);
        int a3 = min(max(adj[min(j3, end - 1)], 0), N - 1);
        float y0 = Y[(size_t)a0 * 8 + o];
        float y1 = Y[(size_t)a1 * 8 + o];
        float y2 = Y[(size_t)a2 * 8 + o];
        float y3 = Y[(size_t)a3 * 8 + o];
        s += y0;
        s = fmaf(y1, m1, s);
        s = fmaf(y2, m2, s);
        s = fmaf(y3, m3, s);
    }
    float acc = s / fmaxf((float)(end - beg), 1.f) + R[(size_t)n * 8 + o];
    float mx = acc;
#pragma unroll
    for (int d = 1; d < 8; d <<= 1) mx = fmaxf(mx, __shfl_xor(mx, d, 64));
    float ex = expf(acc - mx), se = ex;
#pragma unroll
    for (int d = 1; d < 8; d <<= 1) se += __shfl_xor(se, d, 64);
    float v = acc - mx - logf(se);
    if (*flag) ((float*)Out)[(size_t)n * 8 + o] = v;
    else       ((u16*)Out)[(size_t)n * 8 + o] = f2bf(v);
}

// ---------------- launch ----------------
extern "C" void kernel_launch(void* const* d_in, const int* in_sizes, int n_in,
                              void* d_out, int out_size, void* d_ws, size_t ws_size,
                              hipStream_t stream) {
    const void* x   = d_in[0];
    const int* ei   = (const int*)d_in[1];
    const int N = in_sizes[0] / 128;
    const int E = in_sizes[1] / 2;
    const int* srcv = ei;
    const int* dstv = ei + E;
    const int NBUK = (N + 255) >> 8;         // buckets of 256 nodes
    const int bucketed = (NBUK <= 256) ? 1 : 0;
    const int chunk = (E + NCB - 1) / NCB;
    const int cvtB = (N * 16 + 255) / 256;
    const int nbA = (N + 511) / 512;

    auto rnd = [](size_t b) { return (b + 255) & ~(size_t)255; };
    size_t need = rnd(256)                    // flag
                + rnd((size_t)N * 4)          // deg (fallback)
                + rnd((size_t)N * 4)          // r0 (fallback)
                + rnd((size_t)(N + 1) * 4)    // rowptr
                + rnd(4096)                   // bsums (fallback)
                + rnd(256 * NCB * 4)          // C matrix
                + rnd(1024) + rnd(1024)       // T, B
                + rnd((size_t)E * 4)          // adj
                + 2 * rnd((size_t)N * 256)    // X, A
                + 2 * rnd((size_t)N * 32)     // Y, R
                + 4 * rnd(32768) + 2 * rnd(2048) + 2 * rnd(512) + rnd(64);
    if (ws_size < need) {
        k_sentinel<<<(out_size + 255) / 256, 256, 0, stream>>>((u16*)d_out, out_size);
        return;
    }

    char* p = (char*)d_ws;
    auto carve = [&](size_t bytes) { char* r = p; p += (bytes + 255) & ~(size_t)255; return r; };
    int* flag   = (int*)carve(256);
    int* deg    = (int*)carve((size_t)N * 4);
    int* r0     = (int*)carve((size_t)N * 4);
    int* rowptr = (int*)carve((size_t)(N + 1) * 4);
    int* bsums  = (int*)carve(4096);
    int* C      = (int*)carve(256 * NCB * 4);
    int* T      = (int*)carve(1024);
    int* B      = (int*)carve(1024);
    int* adj    = (int*)carve((size_t)E * 4);
    u32* X      = (u32*)carve((size_t)N * 256);   // [N,128] packed bf16
    u32* A      = (u32*)carve((size_t)N * 256);   // agg buffer
    float* Y    = (float*)carve((size_t)N * 32);  // [N,8] f32
    float* R    = (float*)carve((size_t)N * 32);
    u32* w1l = (u32*)carve(32768); u32* w1r = (u32*)carve(32768);
    u32* whl = (u32*)carve(32768); u32* whr = (u32*)carve(32768);
    u32* w2l = (u32*)carve(2048);  u32* w2r = (u32*)carve(2048);
    float* bf1 = (float*)carve(512); float* bfh = (float*)carve(512);
    float* bf2 = (float*)carve(64);
    u32* pairs = A;                  // consumed by k_fillb2 before first aggregate
    (void)n_in;

    // 1: convert x + params + bucket count (inline dtype detect, LDS-only atomics)
    k_front<<<cvtB + 134 + (bucketed ? 256 : 0), 256, 0, stream>>>(
        x, dstv, flag, bucketed, (uint4*)X, C, E, N, chunk, cvtB,
        d_in[3], d_in[5], d_in[6], d_in[8], d_in[9], d_in[11],
        d_in[4], d_in[7], d_in[10],
        w1l, w1r, whl, whr, w2l, w2r, bf1, bfh, bf2);
    if (bucketed) {
        k_scanT<<<NBUK, 256, 0, stream>>>(C, T);
        k_scanB<<<1, 256, 0, stream>>>(T, B, NBUK);
        k_place<<<NCB, 256, 0, stream>>>(srcv, dstv, C, B, pairs, E, N, chunk);
        k_fillb2<<<NBUK, 256, 0, stream>>>(pairs, B, T, rowptr, adj, E, N, NBUK);
    } else {
        k_zero<<<(N + 255) / 256, 256, 0, stream>>>(deg, N);
        k_deg<<<(E + 255) / 256, 256, 0, stream>>>(dstv, deg, E, N);
        k_scan1<<<nbA, 512, 0, stream>>>(deg, r0, bsums, N);
        k_scan2f<<<1, 128, 0, stream>>>(bsums, nbA);
        k_scan3f<<<nbA, 512, 0, stream>>>(r0, bsums, rowptr, N, E);
        k_fill<<<(E + 255) / 256, 256, 0, stream>>>(srcv, dstv, rowptr, deg, adj, E, N);
    }

    int aggBlocks = (int)(((size_t)N * 64 + 255) / 256);
    int tiles = (N + 15) / 16;
    int gemmBlocks = (tiles + 7) / 8;     // 8 waves/block (512 threads)
    int perNode8 = (int)(((size_t)N * 8 + 255) / 256);

    // L1: A=mean(X); h1=relu(A@W1l^T+b1+X@W1r^T) -> X (own-rows aliasing, safe)
    k_aggregate<<<aggBlocks, 256, 0, stream>>>((const uint4*)X, rowptr, adj, (uint4*)A, N, E);
    k_gemm128<<<gemmBlocks, 512, 0, stream>>>((const u16*)A, (const u16*)X, w1l, w1r, bf1, (u16*)X, N);
    // L2: A=mean(h1); fused gemm+elu+head -> Y,R (h2 never materialized)
    k_aggregate<<<aggBlocks, 256, 0, stream>>>((const uint4*)X, rowptr, adj, (uint4*)A, N, E);
    k_gemm2<<<gemmBlocks, 512, 0, stream>>>((const u16*)A, (const u16*)X, whl, whr, bfh,
                                            w2l, w2r, bf2, Y, R, N);
    // out = log_softmax(mean_agg(Y) + R)
    k_agg8sm<<<perNode8, 256, 0, stream>>>(Y, R, rowptr, adj, flag, d_out, N, E);
}